// Round 1
// baseline (658.842 us; speedup 1.0000x reference)
//
#include <hip/hip_runtime.h>

#define NN 100000   // nodes
#define NE 800000   // edges
#define NF 500      // in features
#define NH 64       // hidden
#define NC 16       // classes

// ---------------- counting-sort-by-dst: histogram ----------------
__global__ void k_hist(const int* __restrict__ dst, int* __restrict__ deg) {
    int e = blockIdx.x * 256 + threadIdx.x;
    if (e < NE) atomicAdd(&deg[dst[e]], 1);
}

// ---------------- exclusive scan (single block); deg[] becomes cursor[] ----------------
__global__ __launch_bounds__(1024) void k_scan(int* __restrict__ deg, int* __restrict__ start) {
    __shared__ int ssum[1024];
    const int t = threadIdx.x;
    const int CH = 98;                       // 1024*98 >= 100000
    int lo = t * CH, hi = lo + CH;
    if (hi > NN) hi = NN;
    if (lo > NN) lo = NN;
    int s = 0;
    for (int i = lo; i < hi; ++i) s += deg[i];
    ssum[t] = s;
    __syncthreads();
    for (int off = 1; off < 1024; off <<= 1) {
        int v = (t >= off) ? ssum[t - off] : 0;
        __syncthreads();
        ssum[t] += v;
        __syncthreads();
    }
    int run = (t == 0) ? 0 : ssum[t - 1];
    for (int i = lo; i < hi; ++i) {
        int d = deg[i];
        start[i] = run;
        deg[i] = run;                        // becomes cursor for scatter
        run += d;
    }
    if (t == 1023) start[NN] = run;          // = NE
}

// ---------------- scatter edges into CSR order ----------------
__global__ void k_scatter(const int* __restrict__ src, const int* __restrict__ dst,
                          const float* __restrict__ ew, int* __restrict__ cursor,
                          int* __restrict__ psrc, float* __restrict__ pw) {
    int e = blockIdx.x * 256 + threadIdx.x;
    if (e < NE) {
        int p = atomicAdd(&cursor[dst[e]], 1);
        psrc[p] = src[e];
        pw[p]   = ew[e];
    }
}

// ---------------- GEMM1: h1 = x @ W1  (100000x500x64, fp32) ----------------
// 256 threads, 256x64 tile, 8x8 per thread, K-tile 32 (k-unroll 4, all b128 LDS reads).
__global__ __launch_bounds__(256, 2) void k_gemm1(const float* __restrict__ x,
                                                  const float* __restrict__ W1,
                                                  float* __restrict__ h1) {
    __shared__ float xs[256 * 32];           // swizzled: elem (m,k) at m*32 + ((k>>2)^((m>>3)&7))*4 + (k&3)
    __shared__ float ws[32 * 64];
    const int tid  = threadIdx.x;
    const int row0 = blockIdx.x * 256;
    const int tx = tid & 7;                  // cols tx*8 .. tx*8+7
    const int ty = tid >> 3;                 // rows ty*8 .. ty*8+7
    float4 acc[8][2];
#pragma unroll
    for (int i = 0; i < 8; ++i) { acc[i][0] = make_float4(0,0,0,0); acc[i][1] = make_float4(0,0,0,0); }

    const int lr = tid >> 3;                 // staging row within pass (0..31)
    const int kq = tid & 7;                  // staging k-quad (0..7)

    for (int k0 = 0; k0 < NF; k0 += 32) {
        // stage x tile: 256 rows x 32 k
#pragma unroll
        for (int p = 0; p < 8; ++p) {
            int m  = lr + p * 32;
            int gm = row0 + m;
            int gk = k0 + kq * 4;
            float4 v = make_float4(0.f, 0.f, 0.f, 0.f);
            if (gm < NN && gk + 4 <= NF) v = *(const float4*)(x + (long)gm * NF + gk);
            int slot = kq ^ ((m >> 3) & 7);
            *(float4*)(xs + m * 32 + slot * 4) = v;
        }
        // stage W1 tile: 32 k x 64 n
        for (int idx = tid; idx < 2048; idx += 256) {
            int k = idx >> 6, n = idx & 63;
            ws[idx] = (k0 + k < NF) ? W1[(k0 + k) * NH + n] : 0.f;
        }
        __syncthreads();
#pragma unroll
        for (int kk = 0; kk < 32; kk += 4) {
            const int slot = (kk >> 2) ^ (ty & 7);
            float4 xv[8];
#pragma unroll
            for (int i = 0; i < 8; ++i)
                xv[i] = *(const float4*)(xs + (ty * 8 + i) * 32 + slot * 4);
#pragma unroll
            for (int j = 0; j < 4; ++j) {
                float4 wa = *(const float4*)(ws + (kk + j) * 64 + tx * 8);
                float4 wb = *(const float4*)(ws + (kk + j) * 64 + tx * 8 + 4);
#pragma unroll
                for (int i = 0; i < 8; ++i) {
                    float xij = (j == 0) ? xv[i].x : (j == 1) ? xv[i].y : (j == 2) ? xv[i].z : xv[i].w;
                    acc[i][0].x += xij * wa.x; acc[i][0].y += xij * wa.y;
                    acc[i][0].z += xij * wa.z; acc[i][0].w += xij * wa.w;
                    acc[i][1].x += xij * wb.x; acc[i][1].y += xij * wb.y;
                    acc[i][1].z += xij * wb.z; acc[i][1].w += xij * wb.w;
                }
            }
        }
        __syncthreads();
    }
#pragma unroll
    for (int i = 0; i < 8; ++i) {
        int gm = row0 + ty * 8 + i;
        if (gm < NN) {
            *(float4*)(h1 + (long)gm * NH + tx * 8)     = acc[i][0];
            *(float4*)(h1 + (long)gm * NH + tx * 8 + 4) = acc[i][1];
        }
    }
}

// ---------------- SpMM1 + bias + ReLU: h = relu(A @ h1 + b1) ----------------
// one wave per node, 64 lanes = 64 features
__global__ __launch_bounds__(256) void k_spmm1(const int* __restrict__ start,
                                               const int* __restrict__ psrc,
                                               const float* __restrict__ pw,
                                               const float* __restrict__ h1,
                                               const float* __restrict__ b1,
                                               float* __restrict__ h) {
    int wid  = (blockIdx.x * blockDim.x + threadIdx.x) >> 6;
    int lane = threadIdx.x & 63;
    if (wid >= NN) return;
    int s = start[wid], e = start[wid + 1];
    float acc = 0.f;
    for (int p = s; p < e; ++p) {
        float wv = pw[p];
        int   sn = psrc[p];
        acc += wv * h1[(long)sn * NH + lane];
    }
    float v = acc + b1[lane];
    h[(long)wid * NH + lane] = fmaxf(v, 0.f);
}

// ---------------- GEMM2: h2 = h @ W2  (100000x64x16) ----------------
__global__ __launch_bounds__(256) void k_gemm2(const float* __restrict__ h,
                                               const float* __restrict__ W2,
                                               float* __restrict__ h2) {
    __shared__ float hs[64][65];
    __shared__ float w2s[64 * 16];
    const int tid  = threadIdx.x;
    const int row0 = blockIdx.x * 64;
    for (int idx = tid; idx < 1024; idx += 256) w2s[idx] = W2[idx];
    for (int idx = tid; idx < 4096; idx += 256) {
        int m = idx >> 6, k = idx & 63;
        int gm = row0 + m;
        hs[m][k] = (gm < NN) ? h[(long)gm * NH + k] : 0.f;
    }
    __syncthreads();
    const int n = tid & 15, mq = tid >> 4;
    float a0 = 0.f, a1 = 0.f, a2 = 0.f, a3 = 0.f;
#pragma unroll 8
    for (int k = 0; k < 64; ++k) {
        float wv = w2s[k * 16 + n];
        a0 += hs[mq * 4 + 0][k] * wv;
        a1 += hs[mq * 4 + 1][k] * wv;
        a2 += hs[mq * 4 + 2][k] * wv;
        a3 += hs[mq * 4 + 3][k] * wv;
    }
    int m0 = row0 + mq * 4;
    if (m0 + 0 < NN) h2[(long)(m0 + 0) * NC + n] = a0;
    if (m0 + 1 < NN) h2[(long)(m0 + 1) * NC + n] = a1;
    if (m0 + 2 < NN) h2[(long)(m0 + 2) * NC + n] = a2;
    if (m0 + 3 < NN) h2[(long)(m0 + 3) * NC + n] = a3;
}

// ---------------- SpMM2 + bias: out = A @ h2 + b2 ----------------
// one wave per node: 16 features x 4 parallel edge-slots, shuffle-reduce
__global__ __launch_bounds__(256) void k_spmm2(const int* __restrict__ start,
                                               const int* __restrict__ psrc,
                                               const float* __restrict__ pw,
                                               const float* __restrict__ h2,
                                               const float* __restrict__ b2,
                                               float* __restrict__ out) {
    int wid  = (blockIdx.x * blockDim.x + threadIdx.x) >> 6;
    int lane = threadIdx.x & 63;
    if (wid >= NN) return;
    int f  = lane & 15;
    int es = lane >> 4;
    int s = start[wid], e = start[wid + 1];
    float acc = 0.f;
    for (int p = s + es; p < e; p += 4)
        acc += pw[p] * h2[(long)psrc[p] * NC + f];
    acc += __shfl_xor(acc, 16, 64);
    acc += __shfl_xor(acc, 32, 64);
    if (es == 0) out[(long)wid * NC + f] = acc + b2[f];
}

extern "C" void kernel_launch(void* const* d_in, const int* in_sizes, int n_in,
                              void* d_out, int out_size, void* d_ws, size_t ws_size,
                              hipStream_t stream) {
    const float* x   = (const float*)d_in[0];
    const float* W1  = (const float*)d_in[1];
    const float* b1  = (const float*)d_in[2];
    const float* W2  = (const float*)d_in[3];
    const float* b2  = (const float*)d_in[4];
    const float* ew  = (const float*)d_in[5];
    const int*   src = (const int*)d_in[6];
    const int*   dst = (const int*)d_in[7];
    float* out = (float*)d_out;

    // workspace layout (58.4 MB total)
    char* w = (char*)d_ws;
    float* h1     = (float*)(w + 0);            // 25.6 MB (reused as h2 after h1 is dead)
    float* hbuf   = (float*)(w + 25600000);     // 25.6 MB  relu(spmm1)
    int*   startp = (int*)  (w + 51200000);     // 400016 B (100001 ints)
    int*   cursor = (int*)  (w + 51600016);     // 400000 B (deg -> cursor)
    int*   psrc   = (int*)  (w + 52000016);     // 3.2 MB
    float* pw     = (float*)(w + 55200016);     // 3.2 MB
    float* h2     = h1;

    hipMemsetAsync(cursor, 0, NN * sizeof(int), stream);
    k_hist   <<<(NE + 255) / 256, 256, 0, stream>>>(dst, cursor);
    k_scan   <<<1, 1024, 0, stream>>>(cursor, startp);
    k_scatter<<<(NE + 255) / 256, 256, 0, stream>>>(src, dst, ew, cursor, psrc, pw);
    k_gemm1  <<<(NN + 255) / 256, 256, 0, stream>>>(x, W1, h1);
    k_spmm1  <<<(NN * 64) / 256, 256, 0, stream>>>(startp, psrc, pw, h1, b1, hbuf);
    k_gemm2  <<<(NN + 63) / 64, 256, 0, stream>>>(hbuf, W2, h2);
    k_spmm2  <<<(NN * 64) / 256, 256, 0, stream>>>(startp, psrc, pw, h2, b2, out);
}

// Round 2
// 236.104 us; speedup vs baseline: 2.7905x; 2.7905x over previous
//
#include <hip/hip_runtime.h>

#define NN 100000   // nodes
#define NE 800000   // edges
#define NF 500      // in features
#define NH 64       // hidden
#define NC 16       // classes
#define SCAN_B 98   // 98 * 1024 >= NN

typedef __attribute__((ext_vector_type(4))) float f32x4;
typedef __attribute__((ext_vector_type(8))) short bf16x8;  // 8 bf16 (4 VGPRs)

__device__ inline unsigned int f2bf(float f) {
    union { float f; unsigned int u; } v; v.f = f;
    return (v.u + 0x7FFFu + ((v.u >> 16) & 1u)) >> 16;   // RNE
}

// ---------------- counting-sort-by-dst: histogram ----------------
__global__ void k_hist(const int* __restrict__ dst, int* __restrict__ deg) {
    int e = blockIdx.x * 256 + threadIdx.x;
    if (e < NE) atomicAdd(&deg[dst[e]], 1);
}

// ---------------- scan stage A: per-block sums (coalesced) ----------------
__global__ __launch_bounds__(1024) void k_scanA(const int* __restrict__ deg, int* __restrict__ bsum) {
    __shared__ int s[1024];
    int t = threadIdx.x, i = blockIdx.x * 1024 + t;
    s[t] = (i < NN) ? deg[i] : 0;
    __syncthreads();
    for (int off = 512; off > 0; off >>= 1) {
        if (t < off) s[t] += s[t + off];
        __syncthreads();
    }
    if (t == 0) bsum[blockIdx.x] = s[0];
}

// ---------------- scan stage B: scan the 98 block sums ----------------
__global__ __launch_bounds__(128) void k_scanB(int* __restrict__ bsum, int* __restrict__ start) {
    __shared__ int s[128];
    int t = threadIdx.x;
    int v = (t < SCAN_B) ? bsum[t] : 0;
    s[t] = v;
    __syncthreads();
    for (int off = 1; off < 128; off <<= 1) {
        int u = (t >= off) ? s[t - off] : 0;
        __syncthreads();
        s[t] += u;
        __syncthreads();
    }
    if (t < SCAN_B) bsum[t] = s[t] - v;       // exclusive block base
    if (t == SCAN_B - 1) start[NN] = s[t];    // total = NE
}

// ---------------- scan stage C: block-local scan + base -> start, cursor ----------------
__global__ __launch_bounds__(1024) void k_scanC(const int* __restrict__ deg, const int* __restrict__ bsum,
                                                int* __restrict__ start, int* __restrict__ cursor) {
    __shared__ int s[1024];
    int t = threadIdx.x, i = blockIdx.x * 1024 + t;
    int d = (i < NN) ? deg[i] : 0;
    s[t] = d;
    __syncthreads();
    for (int off = 1; off < 1024; off <<= 1) {
        int u = (t >= off) ? s[t - off] : 0;
        __syncthreads();
        s[t] += u;
        __syncthreads();
    }
    if (i < NN) {
        int ex = bsum[blockIdx.x] + s[t] - d;
        start[i] = ex;
        cursor[i] = ex;
    }
}

// ---------------- scatter edges into CSR order ----------------
__global__ void k_scatter(const int* __restrict__ src, const int* __restrict__ dst,
                          const float* __restrict__ ew, int* __restrict__ cursor,
                          int* __restrict__ psrc, float* __restrict__ pw) {
    int e = blockIdx.x * 256 + threadIdx.x;
    if (e < NE) {
        int p = atomicAdd(&cursor[dst[e]], 1);
        psrc[p] = src[e];
        pw[p]   = ew[e];
    }
}

// ---------------- GEMM1 (MFMA bf16): h1 = x @ W1, fp32 accum ----------------
// 128x64 tile, 256 threads (4 waves), wave w -> rows w*32..w*32+31 (2x4 16x16 frags).
// LDS: xs [128][64] bf16 swizzled (slot ^= row&7), ws = W1^T [n][k] bf16 swizzled.
__global__ __launch_bounds__(256) void k_gemm1(const float* __restrict__ x,
                                               const float* __restrict__ W1,
                                               float* __restrict__ h1) {
    __shared__ unsigned short xs[128 * 64];   // 16 KB
    __shared__ unsigned short ws[64 * 64];    // 8 KB
    const int tid  = threadIdx.x;
    const int lane = tid & 63;
    const int wv   = tid >> 6;
    const int row0 = blockIdx.x * 128;

    f32x4 acc[2][4];
#pragma unroll
    for (int i = 0; i < 2; ++i)
#pragma unroll
        for (int j = 0; j < 4; ++j) acc[i][j] = (f32x4){0.f, 0.f, 0.f, 0.f};

    for (int k0 = 0; k0 < NF; k0 += 64) {
        // stage x tile: 1024 units of (row, 8k-slot), 4 per thread
#pragma unroll
        for (int p = 0; p < 4; ++p) {
            int u  = tid + p * 256;
            int r  = u >> 3, sl = u & 7;
            int gm = row0 + r, gk = k0 + sl * 8;
            float e[8];
            if (gm < NN && gk + 8 <= NF) {
                float4 va = *(const float4*)(x + (long)gm * NF + gk);
                float4 vb = *(const float4*)(x + (long)gm * NF + gk + 4);
                e[0]=va.x; e[1]=va.y; e[2]=va.z; e[3]=va.w;
                e[4]=vb.x; e[5]=vb.y; e[6]=vb.z; e[7]=vb.w;
            } else {
#pragma unroll
                for (int j = 0; j < 8; ++j)
                    e[j] = (gm < NN && gk + j < NF) ? x[(long)gm * NF + gk + j] : 0.f;
            }
            uint4 pk;
            pk.x = f2bf(e[0]) | (f2bf(e[1]) << 16);
            pk.y = f2bf(e[2]) | (f2bf(e[3]) << 16);
            pk.z = f2bf(e[4]) | (f2bf(e[5]) << 16);
            pk.w = f2bf(e[6]) | (f2bf(e[7]) << 16);
            *(uint4*)(xs + r * 64 + (sl ^ (r & 7)) * 8) = pk;
        }
        // stage W1^T tile: 512 units of (n, 8k-slot), 2 per thread; lanes->consecutive n (coalesced per j)
#pragma unroll
        for (int p = 0; p < 2; ++p) {
            int u  = tid + p * 256;
            int n  = u & 63, sl = u >> 6;
            int gk = k0 + sl * 8;
            float e[8];
#pragma unroll
            for (int j = 0; j < 8; ++j)
                e[j] = (gk + j < NF) ? W1[(long)(gk + j) * NH + n] : 0.f;
            uint4 pk;
            pk.x = f2bf(e[0]) | (f2bf(e[1]) << 16);
            pk.y = f2bf(e[2]) | (f2bf(e[3]) << 16);
            pk.z = f2bf(e[4]) | (f2bf(e[5]) << 16);
            pk.w = f2bf(e[6]) | (f2bf(e[7]) << 16);
            *(uint4*)(ws + n * 64 + (sl ^ (n & 7)) * 8) = pk;
        }
        __syncthreads();
#pragma unroll
        for (int ks = 0; ks < 2; ++ks) {
            const int kg = ks * 4 + (lane >> 4);       // k-slot for this lane's 8 elems
            bf16x8 af[2], bfr[4];
#pragma unroll
            for (int i = 0; i < 2; ++i) {
                int r = wv * 32 + i * 16 + (lane & 15);
                af[i] = *(const bf16x8*)(xs + r * 64 + (kg ^ (r & 7)) * 8);
            }
#pragma unroll
            for (int j = 0; j < 4; ++j) {
                int n = j * 16 + (lane & 15);
                bfr[j] = *(const bf16x8*)(ws + n * 64 + (kg ^ (n & 7)) * 8);
            }
#pragma unroll
            for (int i = 0; i < 2; ++i)
#pragma unroll
                for (int j = 0; j < 4; ++j)
                    acc[i][j] = __builtin_amdgcn_mfma_f32_16x16x32_bf16(af[i], bfr[j], acc[i][j], 0, 0, 0);
        }
        __syncthreads();
    }
    // C/D layout: col = lane&15, row = (lane>>4)*4 + q
#pragma unroll
    for (int i = 0; i < 2; ++i) {
        int mbase = row0 + wv * 32 + i * 16 + (lane >> 4) * 4;
#pragma unroll
        for (int q = 0; q < 4; ++q) {
            int gm = mbase + q;
            if (gm < NN) {
#pragma unroll
                for (int j = 0; j < 4; ++j)
                    h1[(long)gm * NH + j * 16 + (lane & 15)] = acc[i][j][q];
            }
        }
    }
}

// ---------------- SpMM1 + bias + ReLU: 4 edge-slots x 16 float4-features ----------------
__global__ __launch_bounds__(256) void k_spmm1(const int* __restrict__ start,
                                               const int* __restrict__ psrc,
                                               const float* __restrict__ pw,
                                               const float* __restrict__ h1,
                                               const float* __restrict__ b1,
                                               float* __restrict__ h) {
    int wid  = (blockIdx.x * 256 + threadIdx.x) >> 6;
    int lane = threadIdx.x & 63;
    if (wid >= NN) return;
    int f4 = lane & 15, es = lane >> 4;
    int s = start[wid], e = start[wid + 1];
    float4 acc = make_float4(0.f, 0.f, 0.f, 0.f);
    for (int p = s + es; p < e; p += 4) {
        float wgt = pw[p];
        const float4 v = *(const float4*)(h1 + (long)psrc[p] * NH + f4 * 4);
        acc.x += wgt * v.x; acc.y += wgt * v.y;
        acc.z += wgt * v.z; acc.w += wgt * v.w;
    }
    acc.x += __shfl_xor(acc.x, 16, 64); acc.y += __shfl_xor(acc.y, 16, 64);
    acc.z += __shfl_xor(acc.z, 16, 64); acc.w += __shfl_xor(acc.w, 16, 64);
    acc.x += __shfl_xor(acc.x, 32, 64); acc.y += __shfl_xor(acc.y, 32, 64);
    acc.z += __shfl_xor(acc.z, 32, 64); acc.w += __shfl_xor(acc.w, 32, 64);
    if (es == 0) {
        const float4 b = *(const float4*)(b1 + f4 * 4);
        float4 r;
        r.x = fmaxf(acc.x + b.x, 0.f);
        r.y = fmaxf(acc.y + b.y, 0.f);
        r.z = fmaxf(acc.z + b.z, 0.f);
        r.w = fmaxf(acc.w + b.w, 0.f);
        *(float4*)(h + (long)wid * NH + f4 * 4) = r;
    }
}

// ---------------- GEMM2: h2 = h @ W2  (100000x64x16) ----------------
__global__ __launch_bounds__(256) void k_gemm2(const float* __restrict__ h,
                                               const float* __restrict__ W2,
                                               float* __restrict__ h2) {
    __shared__ float hs[64][65];
    __shared__ float w2s[64 * 16];
    const int tid  = threadIdx.x;
    const int row0 = blockIdx.x * 64;
    for (int idx = tid; idx < 1024; idx += 256) w2s[idx] = W2[idx];
    for (int idx = tid; idx < 4096; idx += 256) {
        int m = idx >> 6, k = idx & 63;
        int gm = row0 + m;
        hs[m][k] = (gm < NN) ? h[(long)gm * NH + k] : 0.f;
    }
    __syncthreads();
    const int n = tid & 15, mq = tid >> 4;
    float a0 = 0.f, a1 = 0.f, a2 = 0.f, a3 = 0.f;
#pragma unroll 8
    for (int k = 0; k < 64; ++k) {
        float wv = w2s[k * 16 + n];
        a0 += hs[mq * 4 + 0][k] * wv;
        a1 += hs[mq * 4 + 1][k] * wv;
        a2 += hs[mq * 4 + 2][k] * wv;
        a3 += hs[mq * 4 + 3][k] * wv;
    }
    int m0 = row0 + mq * 4;
    if (m0 + 0 < NN) h2[(long)(m0 + 0) * NC + n] = a0;
    if (m0 + 1 < NN) h2[(long)(m0 + 1) * NC + n] = a1;
    if (m0 + 2 < NN) h2[(long)(m0 + 2) * NC + n] = a2;
    if (m0 + 3 < NN) h2[(long)(m0 + 3) * NC + n] = a3;
}

// ---------------- SpMM2 + bias: 16 edge-slots x 4 float4-features ----------------
__global__ __launch_bounds__(256) void k_spmm2(const int* __restrict__ start,
                                               const int* __restrict__ psrc,
                                               const float* __restrict__ pw,
                                               const float* __restrict__ h2,
                                               const float* __restrict__ b2,
                                               float* __restrict__ out) {
    int wid  = (blockIdx.x * 256 + threadIdx.x) >> 6;
    int lane = threadIdx.x & 63;
    if (wid >= NN) return;
    int f4 = lane & 3, es = lane >> 2;
    int s = start[wid], e = start[wid + 1];
    float4 acc = make_float4(0.f, 0.f, 0.f, 0.f);
    for (int p = s + es; p < e; p += 16) {
        float wgt = pw[p];
        const float4 v = *(const float4*)(h2 + (long)psrc[p] * NC + f4 * 4);
        acc.x += wgt * v.x; acc.y += wgt * v.y;
        acc.z += wgt * v.z; acc.w += wgt * v.w;
    }
#pragma unroll
    for (int m = 4; m <= 32; m <<= 1) {
        acc.x += __shfl_xor(acc.x, m, 64); acc.y += __shfl_xor(acc.y, m, 64);
        acc.z += __shfl_xor(acc.z, m, 64); acc.w += __shfl_xor(acc.w, m, 64);
    }
    if (es == 0) {
        const float4 b = *(const float4*)(b2 + f4 * 4);
        float4 r;
        r.x = acc.x + b.x; r.y = acc.y + b.y;
        r.z = acc.z + b.z; r.w = acc.w + b.w;
        *(float4*)(out + (long)wid * NC + f4 * 4) = r;
    }
}

extern "C" void kernel_launch(void* const* d_in, const int* in_sizes, int n_in,
                              void* d_out, int out_size, void* d_ws, size_t ws_size,
                              hipStream_t stream) {
    const float* x   = (const float*)d_in[0];
    const float* W1  = (const float*)d_in[1];
    const float* b1  = (const float*)d_in[2];
    const float* W2  = (const float*)d_in[3];
    const float* b2  = (const float*)d_in[4];
    const float* ew  = (const float*)d_in[5];
    const int*   src = (const int*)d_in[6];
    const int*   dst = (const int*)d_in[7];
    float* out = (float*)d_out;

    // workspace layout (58.4 MB, proven footprint)
    char* w = (char*)d_ws;
    float* h1     = (float*)(w + 0);            // 25.6 MB (reused as h2)
    float* hbuf   = (float*)(w + 25600000);     // 25.6 MB  relu(spmm1)
    int*   bsum   = (int*)  (w + 25600000);     // 98 ints, dead before spmm1 writes hbuf
    int*   startp = (int*)  (w + 51200000);     // 100001 ints
    int*   cursor = (int*)  (w + 51600016);     // 100000 ints (deg -> cursor)
    int*   psrc   = (int*)  (w + 52000016);     // 3.2 MB
    float* pw     = (float*)(w + 55200016);     // 3.2 MB
    float* h2     = h1;

    hipMemsetAsync(cursor, 0, NN * sizeof(int), stream);
    k_hist   <<<(NE + 255) / 256, 256, 0, stream>>>(dst, cursor);
    k_scanA  <<<SCAN_B, 1024, 0, stream>>>(cursor, bsum);
    k_scanB  <<<1, 128, 0, stream>>>(bsum, startp);
    k_scanC  <<<SCAN_B, 1024, 0, stream>>>(cursor, bsum, startp, cursor);
    k_scatter<<<(NE + 255) / 256, 256, 0, stream>>>(src, dst, ew, cursor, psrc, pw);
    k_gemm1  <<<(NN + 127) / 128, 256, 0, stream>>>(x, W1, h1);
    k_spmm1  <<<(NN * 64) / 256, 256, 0, stream>>>(startp, psrc, pw, h1, b1, hbuf);
    k_gemm2  <<<(NN + 63) / 64, 256, 0, stream>>>(hbuf, W2, h2);
    k_spmm2  <<<(NN * 64) / 256, 256, 0, stream>>>(startp, psrc, pw, h2, b2, out);
}

// Round 3
// 215.505 us; speedup vs baseline: 3.0572x; 1.0956x over previous
//
#include <hip/hip_runtime.h>

#define NN 100000   // nodes
#define NE 800000   // edges
#define NF 500      // in features
#define NH 64       // hidden
#define NC 16       // classes
#define SCAN_B 98   // 98 * 1024 >= NN
#define G1TILES 782 // ceil(100000/128)
#define G1HALF 391
#define ROLEB 224   // extra hist/scatter blocks fused into gemm1 halves

typedef __attribute__((ext_vector_type(4))) float f32x4;
typedef __attribute__((ext_vector_type(8))) short bf16x8;  // 8 bf16 (4 VGPRs)

__device__ __forceinline__ unsigned int f2bf(float f) {
    union { float f; unsigned int u; } v; v.f = f;
    return (v.u + 0x7FFFu + ((v.u >> 16) & 1u)) >> 16;   // RNE
}
__device__ __forceinline__ float bfbits_lo(unsigned int u) { return __uint_as_float(u << 16); }
__device__ __forceinline__ float bfbits_hi(unsigned int u) { return __uint_as_float(u & 0xffff0000u); }

// ---------------- scan stage A: per-block sums ----------------
__global__ __launch_bounds__(1024) void k_scanA(const int* __restrict__ deg, int* __restrict__ bsum) {
    __shared__ int s[1024];
    int t = threadIdx.x, i = blockIdx.x * 1024 + t;
    s[t] = (i < NN) ? deg[i] : 0;
    __syncthreads();
    for (int off = 512; off > 0; off >>= 1) {
        if (t < off) s[t] += s[t + off];
        __syncthreads();
    }
    if (t == 0) bsum[blockIdx.x] = s[0];
}

// ---------------- scan stage B: scan the 98 block sums ----------------
__global__ __launch_bounds__(128) void k_scanB(int* __restrict__ bsum, int* __restrict__ start) {
    __shared__ int s[128];
    int t = threadIdx.x;
    int v = (t < SCAN_B) ? bsum[t] : 0;
    s[t] = v;
    __syncthreads();
    for (int off = 1; off < 128; off <<= 1) {
        int u = (t >= off) ? s[t - off] : 0;
        __syncthreads();
        s[t] += u;
        __syncthreads();
    }
    if (t < SCAN_B) bsum[t] = s[t] - v;       // exclusive block base
    if (t == SCAN_B - 1) start[NN] = s[t];    // total = NE
}

// ---------------- scan stage C: block-local scan + base -> start, cursor ----------------
__global__ __launch_bounds__(1024) void k_scanC(const int* __restrict__ deg, const int* __restrict__ bsum,
                                                int* __restrict__ start, int* __restrict__ cursor) {
    __shared__ int s[1024];
    int t = threadIdx.x, i = blockIdx.x * 1024 + t;
    int d = (i < NN) ? deg[i] : 0;
    s[t] = d;
    __syncthreads();
    for (int off = 1; off < 1024; off <<= 1) {
        int u = (t >= off) ? s[t - off] : 0;
        __syncthreads();
        s[t] += u;
        __syncthreads();
    }
    if (i < NN) {
        int ex = bsum[blockIdx.x] + s[t] - d;
        start[i] = ex;
        cursor[i] = ex;
    }
}

// ---------------- GEMM1 tile body (MFMA bf16): h1b = bf16(x @ W1) ----------------
// 128x64 tile, 256 threads (4 waves). LDS swizzled as in round 2 (verified).
__device__ __forceinline__ void gemm1_tile(const float* __restrict__ x,
                                           const float* __restrict__ W1,
                                           unsigned short* __restrict__ h1b,
                                           int tile, int tid,
                                           unsigned short* xs, unsigned short* ws) {
    const int lane = tid & 63;
    const int wv   = tid >> 6;
    const int row0 = tile * 128;

    f32x4 acc[2][4];
#pragma unroll
    for (int i = 0; i < 2; ++i)
#pragma unroll
        for (int j = 0; j < 4; ++j) acc[i][j] = (f32x4){0.f, 0.f, 0.f, 0.f};

    for (int k0 = 0; k0 < NF; k0 += 64) {
#pragma unroll
        for (int p = 0; p < 4; ++p) {
            int u  = tid + p * 256;
            int r  = u >> 3, sl = u & 7;
            int gm = row0 + r, gk = k0 + sl * 8;
            float e[8];
            if (gm < NN && gk + 8 <= NF) {
                float4 va = *(const float4*)(x + (long)gm * NF + gk);
                float4 vb = *(const float4*)(x + (long)gm * NF + gk + 4);
                e[0]=va.x; e[1]=va.y; e[2]=va.z; e[3]=va.w;
                e[4]=vb.x; e[5]=vb.y; e[6]=vb.z; e[7]=vb.w;
            } else {
#pragma unroll
                for (int j = 0; j < 8; ++j)
                    e[j] = (gm < NN && gk + j < NF) ? x[(long)gm * NF + gk + j] : 0.f;
            }
            uint4 pk;
            pk.x = f2bf(e[0]) | (f2bf(e[1]) << 16);
            pk.y = f2bf(e[2]) | (f2bf(e[3]) << 16);
            pk.z = f2bf(e[4]) | (f2bf(e[5]) << 16);
            pk.w = f2bf(e[6]) | (f2bf(e[7]) << 16);
            *(uint4*)(xs + r * 64 + (sl ^ (r & 7)) * 8) = pk;
        }
#pragma unroll
        for (int p = 0; p < 2; ++p) {
            int u  = tid + p * 256;
            int n  = u & 63, sl = u >> 6;
            int gk = k0 + sl * 8;
            float e[8];
#pragma unroll
            for (int j = 0; j < 8; ++j)
                e[j] = (gk + j < NF) ? W1[(long)(gk + j) * NH + n] : 0.f;
            uint4 pk;
            pk.x = f2bf(e[0]) | (f2bf(e[1]) << 16);
            pk.y = f2bf(e[2]) | (f2bf(e[3]) << 16);
            pk.z = f2bf(e[4]) | (f2bf(e[5]) << 16);
            pk.w = f2bf(e[6]) | (f2bf(e[7]) << 16);
            *(uint4*)(ws + n * 64 + (sl ^ (n & 7)) * 8) = pk;
        }
        __syncthreads();
#pragma unroll
        for (int ks = 0; ks < 2; ++ks) {
            const int kg = ks * 4 + (lane >> 4);
            bf16x8 af[2], bfr[4];
#pragma unroll
            for (int i = 0; i < 2; ++i) {
                int r = wv * 32 + i * 16 + (lane & 15);
                af[i] = *(const bf16x8*)(xs + r * 64 + (kg ^ (r & 7)) * 8);
            }
#pragma unroll
            for (int j = 0; j < 4; ++j) {
                int n = j * 16 + (lane & 15);
                bfr[j] = *(const bf16x8*)(ws + n * 64 + (kg ^ (n & 7)) * 8);
            }
#pragma unroll
            for (int i = 0; i < 2; ++i)
#pragma unroll
                for (int j = 0; j < 4; ++j)
                    acc[i][j] = __builtin_amdgcn_mfma_f32_16x16x32_bf16(af[i], bfr[j], acc[i][j], 0, 0, 0);
        }
        __syncthreads();
    }
    // C/D: col = lane&15, row = (lane>>4)*4 + q ; store bf16
#pragma unroll
    for (int i = 0; i < 2; ++i) {
        int mbase = row0 + wv * 32 + i * 16 + (lane >> 4) * 4;
#pragma unroll
        for (int q = 0; q < 4; ++q) {
            int gm = mbase + q;
            if (gm < NN) {
#pragma unroll
                for (int j = 0; j < 4; ++j)
                    h1b[(long)gm * NH + j * 16 + (lane & 15)] = (unsigned short)f2bf(acc[i][j][q]);
            }
        }
    }
}

// ---------------- fused: gemm1 half A + degree histogram ----------------
__global__ __launch_bounds__(256) void k_g1a(const float* __restrict__ x, const float* __restrict__ W1,
                                             unsigned short* __restrict__ h1b,
                                             const int* __restrict__ dst, int* __restrict__ deg) {
    __shared__ unsigned short xs[128 * 64];
    __shared__ unsigned short ws[64 * 64];
    int bid = blockIdx.x, tid = threadIdx.x;
    if (bid >= G1HALF) {                       // hist role
        int rb = bid - G1HALF;
        for (int e = rb * 256 + tid; e < NE; e += ROLEB * 256)
            atomicAdd(&deg[dst[e]], 1);
        return;
    }
    gemm1_tile(x, W1, h1b, bid, tid, xs, ws);
}

// ---------------- fused: gemm1 half B + edge scatter ----------------
__global__ __launch_bounds__(256) void k_g1b(const float* __restrict__ x, const float* __restrict__ W1,
                                             unsigned short* __restrict__ h1b,
                                             const int* __restrict__ src, const int* __restrict__ dst,
                                             const float* __restrict__ ew,
                                             int* __restrict__ cursor, int2* __restrict__ edges) {
    __shared__ unsigned short xs[128 * 64];
    __shared__ unsigned short ws[64 * 64];
    int bid = blockIdx.x, tid = threadIdx.x;
    if (bid >= G1HALF) {                       // scatter role
        int rb = bid - G1HALF;
        for (int e = rb * 256 + tid; e < NE; e += ROLEB * 256) {
            int p = atomicAdd(&cursor[dst[e]], 1);
            edges[p] = make_int2(src[e], __float_as_int(ew[e]));
        }
        return;
    }
    gemm1_tile(x, W1, h1b, G1HALF + bid, tid, xs, ws);
}

// ---------------- SpMM1 + bias + ReLU: 8 edge-slots x 8 bf16x8-lanes ----------------
__global__ __launch_bounds__(256) void k_spmm1(const int* __restrict__ start,
                                               const int2* __restrict__ edges,
                                               const unsigned short* __restrict__ h1b,
                                               const float* __restrict__ b1,
                                               unsigned short* __restrict__ hb) {
    int wid  = (blockIdx.x * 256 + threadIdx.x) >> 6;
    int lane = threadIdx.x & 63;
    if (wid >= NN) return;
    int fo = lane & 7, es = lane >> 3;
    int s = start[wid], e = start[wid + 1];
    float a[8] = {0.f, 0.f, 0.f, 0.f, 0.f, 0.f, 0.f, 0.f};
    for (int p = s + es; p < e; p += 8) {
        int2 r = edges[p];
        float w = __int_as_float(r.y);
        const uint4 v = *(const uint4*)(h1b + (long)r.x * NH + fo * 8);
        a[0] += w * bfbits_lo(v.x); a[1] += w * bfbits_hi(v.x);
        a[2] += w * bfbits_lo(v.y); a[3] += w * bfbits_hi(v.y);
        a[4] += w * bfbits_lo(v.z); a[5] += w * bfbits_hi(v.z);
        a[6] += w * bfbits_lo(v.w); a[7] += w * bfbits_hi(v.w);
    }
#pragma unroll
    for (int m = 8; m <= 32; m <<= 1)
#pragma unroll
        for (int j = 0; j < 8; ++j) a[j] += __shfl_xor(a[j], m, 64);
    if (es == 0) {
        float4 ba = *(const float4*)(b1 + fo * 8);
        float4 bb = *(const float4*)(b1 + fo * 8 + 4);
        float r0 = fmaxf(a[0] + ba.x, 0.f), r1 = fmaxf(a[1] + ba.y, 0.f);
        float r2 = fmaxf(a[2] + ba.z, 0.f), r3 = fmaxf(a[3] + ba.w, 0.f);
        float r4 = fmaxf(a[4] + bb.x, 0.f), r5 = fmaxf(a[5] + bb.y, 0.f);
        float r6 = fmaxf(a[6] + bb.z, 0.f), r7 = fmaxf(a[7] + bb.w, 0.f);
        uint4 pk;
        pk.x = f2bf(r0) | (f2bf(r1) << 16);
        pk.y = f2bf(r2) | (f2bf(r3) << 16);
        pk.z = f2bf(r4) | (f2bf(r5) << 16);
        pk.w = f2bf(r6) | (f2bf(r7) << 16);
        *(uint4*)(hb + (long)wid * NH + fo * 8) = pk;
    }
}

// ---------------- GEMM2: h2 = h @ W2  (bf16 h, fp32 accum/out) ----------------
__global__ __launch_bounds__(256) void k_gemm2(const unsigned short* __restrict__ hb,
                                               const float* __restrict__ W2,
                                               float* __restrict__ h2) {
    __shared__ float hs[64][65];
    __shared__ float w2s[64 * 16];
    const int tid  = threadIdx.x;
    const int row0 = blockIdx.x * 64;
    for (int idx = tid; idx < 1024; idx += 256) w2s[idx] = W2[idx];
    for (int idx = tid; idx < 4096; idx += 256) {
        int m = idx >> 6, k = idx & 63;
        int gm = row0 + m;
        hs[m][k] = (gm < NN) ? __uint_as_float(((unsigned int)hb[(long)gm * NH + k]) << 16) : 0.f;
    }
    __syncthreads();
    const int n = tid & 15, mq = tid >> 4;
    float a0 = 0.f, a1 = 0.f, a2 = 0.f, a3 = 0.f;
#pragma unroll 8
    for (int k = 0; k < 64; ++k) {
        float wv = w2s[k * 16 + n];
        a0 += hs[mq * 4 + 0][k] * wv;
        a1 += hs[mq * 4 + 1][k] * wv;
        a2 += hs[mq * 4 + 2][k] * wv;
        a3 += hs[mq * 4 + 3][k] * wv;
    }
    int m0 = row0 + mq * 4;
    if (m0 + 0 < NN) h2[(long)(m0 + 0) * NC + n] = a0;
    if (m0 + 1 < NN) h2[(long)(m0 + 1) * NC + n] = a1;
    if (m0 + 2 < NN) h2[(long)(m0 + 2) * NC + n] = a2;
    if (m0 + 3 < NN) h2[(long)(m0 + 3) * NC + n] = a3;
}

// ---------------- SpMM2 + bias: 16 edge-slots x 4 float4-features ----------------
__global__ __launch_bounds__(256) void k_spmm2(const int* __restrict__ start,
                                               const int2* __restrict__ edges,
                                               const float* __restrict__ h2,
                                               const float* __restrict__ b2,
                                               float* __restrict__ out) {
    int wid  = (blockIdx.x * 256 + threadIdx.x) >> 6;
    int lane = threadIdx.x & 63;
    if (wid >= NN) return;
    int f4 = lane & 3, es = lane >> 2;
    int s = start[wid], e = start[wid + 1];
    float4 acc = make_float4(0.f, 0.f, 0.f, 0.f);
    for (int p = s + es; p < e; p += 16) {
        int2 r = edges[p];
        float wgt = __int_as_float(r.y);
        const float4 v = *(const float4*)(h2 + (long)r.x * NC + f4 * 4);
        acc.x += wgt * v.x; acc.y += wgt * v.y;
        acc.z += wgt * v.z; acc.w += wgt * v.w;
    }
#pragma unroll
    for (int m = 4; m <= 32; m <<= 1) {
        acc.x += __shfl_xor(acc.x, m, 64); acc.y += __shfl_xor(acc.y, m, 64);
        acc.z += __shfl_xor(acc.z, m, 64); acc.w += __shfl_xor(acc.w, m, 64);
    }
    if (es == 0) {
        const float4 b = *(const float4*)(b2 + f4 * 4);
        float4 r;
        r.x = acc.x + b.x; r.y = acc.y + b.y;
        r.z = acc.z + b.z; r.w = acc.w + b.w;
        *(float4*)(out + (long)wid * NC + f4 * 4) = r;
    }
}

extern "C" void kernel_launch(void* const* d_in, const int* in_sizes, int n_in,
                              void* d_out, int out_size, void* d_ws, size_t ws_size,
                              hipStream_t stream) {
    const float* x   = (const float*)d_in[0];
    const float* W1  = (const float*)d_in[1];
    const float* b1  = (const float*)d_in[2];
    const float* W2  = (const float*)d_in[3];
    const float* b2  = (const float*)d_in[4];
    const float* ew  = (const float*)d_in[5];
    const int*   src = (const int*)d_in[6];
    const int*   dst = (const int*)d_in[7];
    float* out = (float*)d_out;

    // workspace layout (<40 MB)
    char* w = (char*)d_ws;
    unsigned short* h1b = (unsigned short*)(w + 0);          // 12.8 MB bf16 x@W1
    unsigned short* hb  = (unsigned short*)(w + 12800000);   // 12.8 MB bf16 relu layer1
    float*          h2  = (float*)(w + 25600000);            // 6.4 MB fp32 h@W2
    int*   bsum   = (int*) (w + 32000000);                   // 98 ints
    int*   startp = (int*) (w + 32001024);                   // 100001 ints
    int*   cursor = (int*) (w + 32402048);                   // 100000 ints (deg -> cursor)
    int2*  edges  = (int2*)(w + 32803072);                   // 6.4 MB (src, w) records

    hipMemsetAsync(cursor, 0, NN * sizeof(int), stream);
    k_g1a  <<<G1HALF + ROLEB, 256, 0, stream>>>(x, W1, h1b, dst, cursor);
    k_scanA<<<SCAN_B, 1024, 0, stream>>>(cursor, bsum);
    k_scanB<<<1, 128, 0, stream>>>(bsum, startp);
    k_scanC<<<SCAN_B, 1024, 0, stream>>>(cursor, bsum, startp, cursor);
    k_g1b  <<<G1HALF + ROLEB, 256, 0, stream>>>(x, W1, h1b, src, dst, ew, cursor, edges);
    k_spmm1<<<(NN * 64) / 256, 256, 0, stream>>>(startp, edges, h1b, b1, hb);
    k_gemm2<<<(NN + 63) / 64, 256, 0, stream>>>(hb, W2, h2);
    k_spmm2<<<(NN * 64) / 256, 256, 0, stream>>>(startp, edges, h2, b2, out);
}

// Round 4
// 204.109 us; speedup vs baseline: 3.2279x; 1.0558x over previous
//
#include <hip/hip_runtime.h>

#define NN 100000   // nodes
#define NE 800000   // edges
#define NF 500      // in features
#define NH 64       // hidden
#define NC 16       // classes
#define SCAN_B 98   // 98 * 1024 >= NN
#define G1TILES 782 // ceil(100000/128)
#define G1HALF 391
#define ROLEB 224   // extra hist/scatter blocks fused into gemm1 halves

typedef __attribute__((ext_vector_type(4))) float f32x4;
typedef __attribute__((ext_vector_type(8))) short bf16x8;  // 8 bf16 (4 VGPRs)

__device__ __forceinline__ unsigned int f2bf(float f) {
    union { float f; unsigned int u; } v; v.f = f;
    return (v.u + 0x7FFFu + ((v.u >> 16) & 1u)) >> 16;   // RNE
}
__device__ __forceinline__ float bfbits_lo(unsigned int u) { return __uint_as_float(u << 16); }
__device__ __forceinline__ float bfbits_hi(unsigned int u) { return __uint_as_float(u & 0xffff0000u); }

// ---------------- zero cursor/deg (replaces pathological hipMemsetAsync fill) ----------------
__global__ __launch_bounds__(256) void k_zero(int4* __restrict__ p) {
    int i = blockIdx.x * 256 + threadIdx.x;          // 25000 int4 = 100000 ints
    if (i < NN / 4) p[i] = make_int4(0, 0, 0, 0);
}

// ---------------- scan stage A: per-block sums ----------------
__global__ __launch_bounds__(1024) void k_scanA(const int* __restrict__ deg, int* __restrict__ bsum) {
    __shared__ int s[1024];
    int t = threadIdx.x, i = blockIdx.x * 1024 + t;
    s[t] = (i < NN) ? deg[i] : 0;
    __syncthreads();
    for (int off = 512; off > 0; off >>= 1) {
        if (t < off) s[t] += s[t + off];
        __syncthreads();
    }
    if (t == 0) bsum[blockIdx.x] = s[0];
}

// ---------------- scan stage B: scan the 98 block sums ----------------
__global__ __launch_bounds__(128) void k_scanB(int* __restrict__ bsum, int* __restrict__ start) {
    __shared__ int s[128];
    int t = threadIdx.x;
    int v = (t < SCAN_B) ? bsum[t] : 0;
    s[t] = v;
    __syncthreads();
    for (int off = 1; off < 128; off <<= 1) {
        int u = (t >= off) ? s[t - off] : 0;
        __syncthreads();
        s[t] += u;
        __syncthreads();
    }
    if (t < SCAN_B) bsum[t] = s[t] - v;       // exclusive block base
    if (t == SCAN_B - 1) start[NN] = s[t];    // total = NE
}

// ---------------- scan stage C: block-local scan + base -> start, cursor ----------------
__global__ __launch_bounds__(1024) void k_scanC(const int* __restrict__ deg, const int* __restrict__ bsum,
                                                int* __restrict__ start, int* __restrict__ cursor) {
    __shared__ int s[1024];
    int t = threadIdx.x, i = blockIdx.x * 1024 + t;
    int d = (i < NN) ? deg[i] : 0;
    s[t] = d;
    __syncthreads();
    for (int off = 1; off < 1024; off <<= 1) {
        int u = (t >= off) ? s[t - off] : 0;
        __syncthreads();
        s[t] += u;
        __syncthreads();
    }
    if (i < NN) {
        int ex = bsum[blockIdx.x] + s[t] - d;
        start[i] = ex;
        cursor[i] = ex;
    }
}

// ---------------- GEMM1 tile body (MFMA bf16): h1b = bf16(x @ W1) ----------------
// 128x64 tile, 256 threads (4 waves). LDS swizzled (verified rounds 2-3).
__device__ __forceinline__ void gemm1_tile(const float* __restrict__ x,
                                           const float* __restrict__ W1,
                                           unsigned short* __restrict__ h1b,
                                           int tile, int tid,
                                           unsigned short* xs, unsigned short* ws) {
    const int lane = tid & 63;
    const int wv   = tid >> 6;
    const int row0 = tile * 128;

    f32x4 acc[2][4];
#pragma unroll
    for (int i = 0; i < 2; ++i)
#pragma unroll
        for (int j = 0; j < 4; ++j) acc[i][j] = (f32x4){0.f, 0.f, 0.f, 0.f};

    for (int k0 = 0; k0 < NF; k0 += 64) {
#pragma unroll
        for (int p = 0; p < 4; ++p) {
            int u  = tid + p * 256;
            int r  = u >> 3, sl = u & 7;
            int gm = row0 + r, gk = k0 + sl * 8;
            float e[8];
            if (gm < NN && gk + 8 <= NF) {
                float4 va = *(const float4*)(x + (long)gm * NF + gk);
                float4 vb = *(const float4*)(x + (long)gm * NF + gk + 4);
                e[0]=va.x; e[1]=va.y; e[2]=va.z; e[3]=va.w;
                e[4]=vb.x; e[5]=vb.y; e[6]=vb.z; e[7]=vb.w;
            } else {
#pragma unroll
                for (int j = 0; j < 8; ++j)
                    e[j] = (gm < NN && gk + j < NF) ? x[(long)gm * NF + gk + j] : 0.f;
            }
            uint4 pk;
            pk.x = f2bf(e[0]) | (f2bf(e[1]) << 16);
            pk.y = f2bf(e[2]) | (f2bf(e[3]) << 16);
            pk.z = f2bf(e[4]) | (f2bf(e[5]) << 16);
            pk.w = f2bf(e[6]) | (f2bf(e[7]) << 16);
            *(uint4*)(xs + r * 64 + (sl ^ (r & 7)) * 8) = pk;
        }
#pragma unroll
        for (int p = 0; p < 2; ++p) {
            int u  = tid + p * 256;
            int n  = u & 63, sl = u >> 6;
            int gk = k0 + sl * 8;
            float e[8];
#pragma unroll
            for (int j = 0; j < 8; ++j)
                e[j] = (gk + j < NF) ? W1[(long)(gk + j) * NH + n] : 0.f;
            uint4 pk;
            pk.x = f2bf(e[0]) | (f2bf(e[1]) << 16);
            pk.y = f2bf(e[2]) | (f2bf(e[3]) << 16);
            pk.z = f2bf(e[4]) | (f2bf(e[5]) << 16);
            pk.w = f2bf(e[6]) | (f2bf(e[7]) << 16);
            *(uint4*)(ws + n * 64 + (sl ^ (n & 7)) * 8) = pk;
        }
        __syncthreads();
#pragma unroll
        for (int ks = 0; ks < 2; ++ks) {
            const int kg = ks * 4 + (lane >> 4);
            bf16x8 af[2], bfr[4];
#pragma unroll
            for (int i = 0; i < 2; ++i) {
                int r = wv * 32 + i * 16 + (lane & 15);
                af[i] = *(const bf16x8*)(xs + r * 64 + (kg ^ (r & 7)) * 8);
            }
#pragma unroll
            for (int j = 0; j < 4; ++j) {
                int n = j * 16 + (lane & 15);
                bfr[j] = *(const bf16x8*)(ws + n * 64 + (kg ^ (n & 7)) * 8);
            }
#pragma unroll
            for (int i = 0; i < 2; ++i)
#pragma unroll
                for (int j = 0; j < 4; ++j)
                    acc[i][j] = __builtin_amdgcn_mfma_f32_16x16x32_bf16(af[i], bfr[j], acc[i][j], 0, 0, 0);
        }
        __syncthreads();
    }
    // C/D: col = lane&15, row = (lane>>4)*4 + q ; store bf16
#pragma unroll
    for (int i = 0; i < 2; ++i) {
        int mbase = row0 + wv * 32 + i * 16 + (lane >> 4) * 4;
#pragma unroll
        for (int q = 0; q < 4; ++q) {
            int gm = mbase + q;
            if (gm < NN) {
#pragma unroll
                for (int j = 0; j < 4; ++j)
                    h1b[(long)gm * NH + j * 16 + (lane & 15)] = (unsigned short)f2bf(acc[i][j][q]);
            }
        }
    }
}

// ---------------- fused: gemm1 half A + degree histogram ----------------
__global__ __launch_bounds__(256) void k_g1a(const float* __restrict__ x, const float* __restrict__ W1,
                                             unsigned short* __restrict__ h1b,
                                             const int* __restrict__ dst, int* __restrict__ deg) {
    __shared__ unsigned short xs[128 * 64];
    __shared__ unsigned short ws[64 * 64];
    int bid = blockIdx.x, tid = threadIdx.x;
    if (bid >= G1HALF) {                       // hist role
        int rb = bid - G1HALF;
        for (int e = rb * 256 + tid; e < NE; e += ROLEB * 256)
            atomicAdd(&deg[dst[e]], 1);
        return;
    }
    gemm1_tile(x, W1, h1b, bid, tid, xs, ws);
}

// ---------------- fused: gemm1 half B + edge scatter ----------------
__global__ __launch_bounds__(256) void k_g1b(const float* __restrict__ x, const float* __restrict__ W1,
                                             unsigned short* __restrict__ h1b,
                                             const int* __restrict__ src, const int* __restrict__ dst,
                                             const float* __restrict__ ew,
                                             int* __restrict__ cursor, int2* __restrict__ edges) {
    __shared__ unsigned short xs[128 * 64];
    __shared__ unsigned short ws[64 * 64];
    int bid = blockIdx.x, tid = threadIdx.x;
    if (bid >= G1HALF) {                       // scatter role
        int rb = bid - G1HALF;
        for (int e = rb * 256 + tid; e < NE; e += ROLEB * 256) {
            int p = atomicAdd(&cursor[dst[e]], 1);
            edges[p] = make_int2(src[e], __float_as_int(ew[e]));
        }
        return;
    }
    gemm1_tile(x, W1, h1b, G1HALF + bid, tid, xs, ws);
}

// ---------------- SpMM1 + bias + ReLU: 8 edge-slots x 8 bf16x8-lanes ----------------
__global__ __launch_bounds__(256) void k_spmm1(const int* __restrict__ start,
                                               const int2* __restrict__ edges,
                                               const unsigned short* __restrict__ h1b,
                                               const float* __restrict__ b1,
                                               unsigned short* __restrict__ hb) {
    int wid  = (blockIdx.x * 256 + threadIdx.x) >> 6;
    int lane = threadIdx.x & 63;
    if (wid >= NN) return;
    int fo = lane & 7, es = lane >> 3;
    int s = start[wid], e = start[wid + 1];
    float a[8] = {0.f, 0.f, 0.f, 0.f, 0.f, 0.f, 0.f, 0.f};
    for (int p = s + es; p < e; p += 8) {
        int2 r = edges[p];
        float w = __int_as_float(r.y);
        const uint4 v = *(const uint4*)(h1b + (long)r.x * NH + fo * 8);
        a[0] += w * bfbits_lo(v.x); a[1] += w * bfbits_hi(v.x);
        a[2] += w * bfbits_lo(v.y); a[3] += w * bfbits_hi(v.y);
        a[4] += w * bfbits_lo(v.z); a[5] += w * bfbits_hi(v.z);
        a[6] += w * bfbits_lo(v.w); a[7] += w * bfbits_hi(v.w);
    }
#pragma unroll
    for (int m = 8; m <= 32; m <<= 1)
#pragma unroll
        for (int j = 0; j < 8; ++j) a[j] += __shfl_xor(a[j], m, 64);
    if (es == 0) {
        float4 ba = *(const float4*)(b1 + fo * 8);
        float4 bb = *(const float4*)(b1 + fo * 8 + 4);
        float r0 = fmaxf(a[0] + ba.x, 0.f), r1 = fmaxf(a[1] + ba.y, 0.f);
        float r2 = fmaxf(a[2] + ba.z, 0.f), r3 = fmaxf(a[3] + ba.w, 0.f);
        float r4 = fmaxf(a[4] + bb.x, 0.f), r5 = fmaxf(a[5] + bb.y, 0.f);
        float r6 = fmaxf(a[6] + bb.z, 0.f), r7 = fmaxf(a[7] + bb.w, 0.f);
        uint4 pk;
        pk.x = f2bf(r0) | (f2bf(r1) << 16);
        pk.y = f2bf(r2) | (f2bf(r3) << 16);
        pk.z = f2bf(r4) | (f2bf(r5) << 16);
        pk.w = f2bf(r6) | (f2bf(r7) << 16);
        *(uint4*)(hb + (long)wid * NH + fo * 8) = pk;
    }
}

// ---------------- GEMM2: h2 = h @ W2  (bf16 h, fp32 accum/out) ----------------
__global__ __launch_bounds__(256) void k_gemm2(const unsigned short* __restrict__ hb,
                                               const float* __restrict__ W2,
                                               float* __restrict__ h2) {
    __shared__ float hs[64][65];
    __shared__ float w2s[64 * 16];
    const int tid  = threadIdx.x;
    const int row0 = blockIdx.x * 64;
    for (int idx = tid; idx < 1024; idx += 256) w2s[idx] = W2[idx];
    for (int idx = tid; idx < 4096; idx += 256) {
        int m = idx >> 6, k = idx & 63;
        int gm = row0 + m;
        hs[m][k] = (gm < NN) ? __uint_as_float(((unsigned int)hb[(long)gm * NH + k]) << 16) : 0.f;
    }
    __syncthreads();
    const int n = tid & 15, mq = tid >> 4;
    float a0 = 0.f, a1 = 0.f, a2 = 0.f, a3 = 0.f;
#pragma unroll 8
    for (int k = 0; k < 64; ++k) {
        float wv = w2s[k * 16 + n];
        a0 += hs[mq * 4 + 0][k] * wv;
        a1 += hs[mq * 4 + 1][k] * wv;
        a2 += hs[mq * 4 + 2][k] * wv;
        a3 += hs[mq * 4 + 3][k] * wv;
    }
    int m0 = row0 + mq * 4;
    if (m0 + 0 < NN) h2[(long)(m0 + 0) * NC + n] = a0;
    if (m0 + 1 < NN) h2[(long)(m0 + 1) * NC + n] = a1;
    if (m0 + 2 < NN) h2[(long)(m0 + 2) * NC + n] = a2;
    if (m0 + 3 < NN) h2[(long)(m0 + 3) * NC + n] = a3;
}

// ---------------- SpMM2 + bias: 16 edge-slots x 4 float4-features ----------------
__global__ __launch_bounds__(256) void k_spmm2(const int* __restrict__ start,
                                               const int2* __restrict__ edges,
                                               const float* __restrict__ h2,
                                               const float* __restrict__ b2,
                                               float* __restrict__ out) {
    int wid  = (blockIdx.x * 256 + threadIdx.x) >> 6;
    int lane = threadIdx.x & 63;
    if (wid >= NN) return;
    int f4 = lane & 3, es = lane >> 2;
    int s = start[wid], e = start[wid + 1];
    float4 acc = make_float4(0.f, 0.f, 0.f, 0.f);
    for (int p = s + es; p < e; p += 16) {
        int2 r = edges[p];
        float wgt = __int_as_float(r.y);
        const float4 v = *(const float4*)(h2 + (long)r.x * NC + f4 * 4);
        acc.x += wgt * v.x; acc.y += wgt * v.y;
        acc.z += wgt * v.z; acc.w += wgt * v.w;
    }
#pragma unroll
    for (int m = 4; m <= 32; m <<= 1) {
        acc.x += __shfl_xor(acc.x, m, 64); acc.y += __shfl_xor(acc.y, m, 64);
        acc.z += __shfl_xor(acc.z, m, 64); acc.w += __shfl_xor(acc.w, m, 64);
    }
    if (es == 0) {
        const float4 b = *(const float4*)(b2 + f4 * 4);
        float4 r;
        r.x = acc.x + b.x; r.y = acc.y + b.y;
        r.z = acc.z + b.z; r.w = acc.w + b.w;
        *(float4*)(out + (long)wid * NC + f4 * 4) = r;
    }
}

extern "C" void kernel_launch(void* const* d_in, const int* in_sizes, int n_in,
                              void* d_out, int out_size, void* d_ws, size_t ws_size,
                              hipStream_t stream) {
    const float* x   = (const float*)d_in[0];
    const float* W1  = (const float*)d_in[1];
    const float* b1  = (const float*)d_in[2];
    const float* W2  = (const float*)d_in[3];
    const float* b2  = (const float*)d_in[4];
    const float* ew  = (const float*)d_in[5];
    const int*   src = (const int*)d_in[6];
    const int*   dst = (const int*)d_in[7];
    float* out = (float*)d_out;

    // workspace layout (<40 MB)
    char* w = (char*)d_ws;
    unsigned short* h1b = (unsigned short*)(w + 0);          // 12.8 MB bf16 x@W1
    unsigned short* hb  = (unsigned short*)(w + 12800000);   // 12.8 MB bf16 relu layer1
    float*          h2  = (float*)(w + 25600000);            // 6.4 MB fp32 h@W2
    int*   bsum   = (int*) (w + 32000000);                   // 98 ints
    int*   startp = (int*) (w + 32001024);                   // 100001 ints
    int*   cursor = (int*) (w + 32402048);                   // 100000 ints (deg -> cursor)
    int2*  edges  = (int2*)(w + 32803072);                   // 6.4 MB (src, w) records

    k_zero <<<(NN / 4 + 255) / 256, 256, 0, stream>>>((int4*)cursor);
    k_g1a  <<<G1HALF + ROLEB, 256, 0, stream>>>(x, W1, h1b, dst, cursor);
    k_scanA<<<SCAN_B, 1024, 0, stream>>>(cursor, bsum);
    k_scanB<<<1, 128, 0, stream>>>(bsum, startp);
    k_scanC<<<SCAN_B, 1024, 0, stream>>>(cursor, bsum, startp, cursor);
    k_g1b  <<<G1HALF + ROLEB, 256, 0, stream>>>(x, W1, h1b, src, dst, ew, cursor, edges);
    k_spmm1<<<(NN * 64) / 256, 256, 0, stream>>>(startp, edges, h1b, b1, hb);
    k_gemm2<<<(NN + 63) / 64, 256, 0, stream>>>(hb, W2, h2);
    k_spmm2<<<(NN * 64) / 256, 256, 0, stream>>>(startp, edges, h2, b2, out);
}